// Round 3
// baseline (697.240 us; speedup 1.0000x reference)
//
#include <hip/hip_runtime.h>

#define NN 10000
#define NE 160000
static constexpr int TPB = 256;

// ---------------- sort / CSR build ----------------

__global__ void k_count(const int* __restrict__ ei, int* __restrict__ cnt_row,
                        int* __restrict__ cnt_col) {
  int e = blockIdx.x * TPB + threadIdx.x;
  if (e >= NE) return;
  atomicAdd(&cnt_row[ei[e]], 1);
  atomicAdd(&cnt_col[ei[NE + e]], 1);
}

__global__ void k_scan2(const int* __restrict__ cnt_r, int* __restrict__ off_r, int* __restrict__ cur_r,
                        const int* __restrict__ cnt_c, int* __restrict__ off_c, int* __restrict__ cur_c) {
  const int* cnt = (blockIdx.x == 0) ? cnt_r : cnt_c;
  int* off = (blockIdx.x == 0) ? off_r : off_c;
  int* cur = (blockIdx.x == 0) ? cur_r : cur_c;
  int lane = threadIdx.x;  // 64 threads (one wave)
  int carry = 0;
  for (int base = 0; base < NN; base += 64) {
    int i = base + lane;
    int v = (i < NN) ? cnt[i] : 0;
    int s = v;
    #pragma unroll
    for (int dd = 1; dd < 64; dd <<= 1) {
      int t = __shfl_up(s, dd, 64);
      if (lane >= dd) s += t;
    }
    int excl = carry + s - v;
    if (i < NN) { off[i] = excl; cur[i] = excl; }
    carry += __shfl(s, 63, 64);
  }
  if (lane == 0) off[NN] = carry;
}

__global__ void k_fill_row(const int* __restrict__ ei, int* __restrict__ cur_row,
                           int* __restrict__ eid_row) {
  int e = blockIdx.x * TPB + threadIdx.x;
  if (e >= NE) return;
  int r = ei[e];
  int p = atomicAdd(&cur_row[r], 1);
  eid_row[p] = e;
}

__global__ void k_fill_col(const int* __restrict__ ei, const int* __restrict__ eid_row,
                           int* __restrict__ cur_col, int* __restrict__ slot_col) {
  int s = blockIdx.x * TPB + threadIdx.x;
  if (s >= NE) return;
  int e = eid_row[s];
  int c = ei[NE + e];
  int p = atomicAdd(&cur_col[c], 1);
  slot_col[p] = s;
}

// ---------------- per-layer kernels ----------------

// xp = x@pw^T + pb ; root = xp@rw^T + cb ; B[n,o] = sum_i xp[i]*eb2[i*D+o]
template<int DIN, int D>
__global__ void __launch_bounds__(TPB)
k_nodeprep(const float* __restrict__ x, const float* __restrict__ pw, const float* __restrict__ pb,
           const float* __restrict__ rw, const float* __restrict__ cb, const float* __restrict__ eb2,
           float* __restrict__ xp, float* __restrict__ root, float* __restrict__ Bb) {
  __shared__ float s_pw[D * DIN], s_rw[D * D], s_eb2[D * D], s_pb[D], s_cb[D];
  for (int t = threadIdx.x; t < D * DIN; t += TPB) s_pw[t] = pw[t];
  for (int t = threadIdx.x; t < D * D; t += TPB) { s_rw[t] = rw[t]; s_eb2[t] = eb2[t]; }
  for (int t = threadIdx.x; t < D; t += TPB) { s_pb[t] = pb[t]; s_cb[t] = cb[t]; }
  __syncthreads();
  int n = blockIdx.x * TPB + threadIdx.x;
  if (n >= NN) return;
  float xv[DIN];
  const float4* x4 = (const float4*)(x + (size_t)n * DIN);
  #pragma unroll
  for (int i = 0; i < DIN / 4; i++) {
    float4 v = x4[i];
    xv[4*i+0] = v.x; xv[4*i+1] = v.y; xv[4*i+2] = v.z; xv[4*i+3] = v.w;
  }
  float xpv[D];
  #pragma unroll
  for (int o = 0; o < D; o++) {
    float a = s_pb[o];
    #pragma unroll
    for (int i = 0; i < DIN; i++) a = fmaf(s_pw[o*DIN + i], xv[i], a);
    xpv[o] = a;
    xp[(size_t)n*D + o] = a;
  }
  #pragma unroll
  for (int o = 0; o < D; o++) {
    float a = s_cb[o];
    #pragma unroll
    for (int i = 0; i < D; i++) a = fmaf(s_rw[o*D + i], xpv[i], a);
    root[(size_t)n*D + o] = a;
  }
  #pragma unroll
  for (int o = 0; o < D; o++) {
    float a = 0.f;
    #pragma unroll
    for (int i = 0; i < D; i++) a = fmaf(xpv[i], s_eb2[i*D + o], a);
    Bb[(size_t)n*D + o] = a;
  }
}

// V[i][k*D+o] = ew2[(i*D+o)*128 + k]   (one-time per layer, 512 KB max)
__global__ void k_trans(const float* __restrict__ ew2, float* __restrict__ V, int D) {
  int t = blockIdx.x * TPB + threadIdx.x;
  int COLS = D * 128;
  if (t >= D * COLS) return;
  int i = t / COLS, c = t - i * COLS;
  int k = c / D, o = c - k * D;
  V[t] = ew2[((size_t)(i * D + o)) * 128 + k];
}

// U[nloc, c] = sum_i xp[n0+nloc, i] * V[i*COLS + c], c = k*D+o
template<int D>
__global__ void __launch_bounds__(TPB)
k_ugemm(const float* __restrict__ xp, const float* __restrict__ V,
        float* __restrict__ U, int n0, int nch) {
  constexpr int COLS = D * 128;
  int c = blockIdx.x * TPB + threadIdx.x;
  int nb = blockIdx.y * 16;
  __shared__ float s_xp[16][D];
  int nload = nch - nb; if (nload > 16) nload = 16;
  for (int t = threadIdx.x; t < 16 * D; t += TPB) {
    int g = t / D, i = t % D;
    s_xp[g][i] = (g < nload) ? xp[(size_t)(n0 + nb + g) * D + i] : 0.f;
  }
  __syncthreads();
  float acc[16];
  #pragma unroll
  for (int g = 0; g < 16; g++) acc[g] = 0.f;
  #pragma unroll
  for (int i = 0; i < D; i++) {
    float t = V[(size_t)i * COLS + c];
    #pragma unroll
    for (int g = 0; g < 16; g++) acc[g] = fmaf(s_xp[g][i], t, acc[g]);
  }
  for (int g = 0; g < nload; g++) U[(size_t)(nb + g) * COLS + c] = acc[g];
}

// One block per source node: stage the node's U row in LDS once, then run all
// of its (row-sorted) edges against it.  D/4 threads per edge.
template<int D>
__global__ void __launch_bounds__(TPB)
k_edgemsg3(const int* __restrict__ eid_row, const int* __restrict__ row_off,
           const float* __restrict__ ea, const float* __restrict__ ew1,
           const float* __restrict__ eb1, const float* __restrict__ U,
           const float* __restrict__ Bb, float* __restrict__ msg, int n0) {
  constexpr int OQ = D / 4;       // threads per edge
  constexpr int EB = TPB / OQ;    // edges per inner iteration
  constexpr int COLS = D * 128;
  int n = n0 + blockIdx.x;
  int p0 = row_off[n], p1 = row_off[n + 1];
  if (p0 >= p1) return;
  __shared__ float s_w1t[8 * 128];    // [i][k]
  __shared__ float s_b1[128];
  __shared__ float s_U[COLS];         // this node's U row: [k][o]
  __shared__ float s_h[EB * 129];     // padded stride kills bank conflicts
  __shared__ float s_ea[EB * 8];
  int tid = threadIdx.x;
  for (int t = tid; t < 1024; t += TPB) {
    int k = t >> 3, i = t & 7;
    s_w1t[i * 128 + k] = ew1[t];
  }
  for (int t = tid; t < 128; t += TPB) s_b1[t] = eb1[t];
  {
    const float4* Ug = (const float4*)(U + (size_t)(n - n0) * COLS);
    float4* Us = (float4*)s_U;
    for (int t = tid; t < COLS / 4; t += TPB) Us[t] = Ug[t];
  }
  int el = tid / OQ, oq = tid % OQ;
  float4 b = ((const float4*)(Bb + (size_t)n * D))[oq];
  for (int pc = p0; pc < p1; pc += EB) {
    int cnt = p1 - pc; if (cnt > EB) cnt = EB;
    __syncthreads();   // first iter: staging done; later: protect s_ea/s_h reuse
    for (int t = tid; t < cnt * 8; t += TPB) {
      int e2 = t >> 3, i = t & 7;
      s_ea[t] = ea[(size_t)eid_row[pc + e2] * 8 + i];
    }
    __syncthreads();
    for (int t = tid; t < cnt * 128; t += TPB) {
      int e2 = t >> 7, k = t & 127;
      float a = s_b1[k];
      #pragma unroll
      for (int i = 0; i < 8; i++) a = fmaf(s_ea[e2 * 8 + i], s_w1t[i * 128 + k], a);
      s_h[e2 * 129 + k] = fmaxf(a, 0.f);
    }
    __syncthreads();
    if (el < cnt) {
      const float* hp = s_h + el * 129;
      const float4* U4 = (const float4*)s_U;
      float4 acc = {0.f, 0.f, 0.f, 0.f};
      #pragma unroll 8
      for (int k = 0; k < 128; k++) {
        float hk = hp[k];
        float4 u = U4[k * OQ + oq];
        acc.x = fmaf(hk, u.x, acc.x);
        acc.y = fmaf(hk, u.y, acc.y);
        acc.z = fmaf(hk, u.z, acc.z);
        acc.w = fmaf(hk, u.w, acc.w);
      }
      acc.x += b.x; acc.y += b.y; acc.z += b.z; acc.w += b.w;
      ((float4*)(msg + (size_t)(pc + el) * D))[oq] = acc;
    }
  }
}

// gather aggregation by col-CSR (deterministic), then x = relu(agg/deg + root) + xp
template<int D>
__global__ void __launch_bounds__(TPB)
k_agg(const int* __restrict__ col_off, const int* __restrict__ slot_col,
      const float* __restrict__ msg, const float* __restrict__ root,
      const float* __restrict__ xp, float* __restrict__ xout) {
  constexpr int GP = TPB / D;
  int g = threadIdx.x / D, o = threadIdx.x % D;
  int n = blockIdx.x * GP + g;
  if (n >= NN) return;
  int p0 = col_off[n], p1 = col_off[n + 1];
  float acc = 0.f;
  for (int p = p0; p < p1; p++) {
    int sc = slot_col[p];
    acc += msg[(size_t)sc * D + o];
  }
  float deg = (p1 > p0) ? (float)(p1 - p0) : 1.f;
  float conv = acc / deg + root[(size_t)n * D + o];
  float rl = conv > 0.f ? conv : 0.f;
  xout[(size_t)n * D + o] = rl + xp[(size_t)n * D + o];
}

// final edge MLP: out = relu((x[row]+x[col]) @ mw0^T + mb0) @ mw1^T + mb1
__global__ void __launch_bounds__(TPB)
k_final(const int* __restrict__ ei, const float* __restrict__ x,
        const float* __restrict__ mw0, const float* __restrict__ mb0,
        const float* __restrict__ mw1, const float* __restrict__ mb1,
        float* __restrict__ out) {
  __shared__ float s_w0[256], s_b0[16], s_w1[16], s_b1;
  for (int t = threadIdx.x; t < 256; t += TPB) s_w0[t] = mw0[t];
  if (threadIdx.x < 16) { s_b0[threadIdx.x] = mb0[threadIdx.x]; s_w1[threadIdx.x] = mw1[threadIdx.x]; }
  if (threadIdx.x == 0) s_b1 = mb1[0];
  __syncthreads();
  int e = blockIdx.x * TPB + threadIdx.x;
  if (e >= NE) return;
  int r = ei[e], c = ei[NE + e];
  const float4* xr4 = (const float4*)(x + (size_t)r * 16);
  const float4* xc4 = (const float4*)(x + (size_t)c * 16);
  float er[16];
  #pragma unroll
  for (int q = 0; q < 4; q++) {
    float4 vr = xr4[q], vc = xc4[q];
    er[4*q+0] = vr.x + vc.x; er[4*q+1] = vr.y + vc.y;
    er[4*q+2] = vr.z + vc.z; er[4*q+3] = vr.w + vc.w;
  }
  float o = s_b1;
  #pragma unroll
  for (int j = 0; j < 16; j++) {
    float t = s_b0[j];
    #pragma unroll
    for (int k = 0; k < 16; k++) t = fmaf(er[k], s_w0[j * 16 + k], t);
    t = fmaxf(t, 0.f);
    o = fmaf(t, s_w1[j], o);
  }
  out[e] = o;
}

// ---------------- host side ----------------

struct LayerPtrs {
  const float *pw, *pb, *ew1, *eb1, *ew2, *eb2, *rw, *cb;
};

template<int DIN, int D>
static void run_layer(const float* xin, float* xout, const LayerPtrs& L,
                      const int* ei, const float* ea,
                      const int* row_off, const int* col_off,
                      const int* eid_row, const int* slot_col,
                      float* xp, float* root, float* Bb, float* msg, float* Vb,
                      float* U, size_t uavail, hipStream_t stream) {
  k_nodeprep<DIN, D><<<(NN + TPB - 1) / TPB, TPB, 0, stream>>>(
      xin, L.pw, L.pb, L.rw, L.cb, L.eb2, xp, root, Bb);
  constexpr int COLS = D * 128;
  k_trans<<<(D * COLS + TPB - 1) / TPB, TPB, 0, stream>>>(L.ew2, Vb, D);
  size_t per_node = sizeof(float) * COLS;
  size_t ch = uavail / per_node;
  int CH = (ch > (size_t)NN) ? NN : (int)ch;
  if (CH < 1) CH = 1;
  for (int n0 = 0; n0 < NN; n0 += CH) {
    int n1 = n0 + CH; if (n1 > NN) n1 = NN;
    int nch = n1 - n0;
    dim3 gb(COLS / TPB, (nch + 15) / 16);
    k_ugemm<D><<<gb, TPB, 0, stream>>>(xp, Vb, U, n0, nch);
    k_edgemsg3<D><<<nch, TPB, 0, stream>>>(
        eid_row, row_off, ea, L.ew1, L.eb1, U, Bb, msg, n0);
  }
  k_agg<D><<<(NN * D + TPB - 1) / TPB, TPB, 0, stream>>>(
      col_off, slot_col, msg, root, xp, xout);
}

extern "C" void kernel_launch(void* const* d_in, const int* in_sizes, int n_in,
                              void* d_out, int out_size, void* d_ws, size_t ws_size,
                              hipStream_t stream) {
  (void)in_sizes; (void)n_in; (void)out_size;
  const float* x0 = (const float*)d_in[0];
  const float* ea = (const float*)d_in[1];
  const int* ei = (const int*)d_in[2];
  LayerPtrs L[4];
  for (int l = 0; l < 4; l++) {
    L[l].pw  = (const float*)d_in[3 + 8 * l];
    L[l].pb  = (const float*)d_in[4 + 8 * l];
    L[l].ew1 = (const float*)d_in[5 + 8 * l];
    L[l].eb1 = (const float*)d_in[6 + 8 * l];
    L[l].ew2 = (const float*)d_in[7 + 8 * l];
    L[l].eb2 = (const float*)d_in[8 + 8 * l];
    L[l].rw  = (const float*)d_in[9 + 8 * l];
    L[l].cb  = (const float*)d_in[10 + 8 * l];
  }
  const float* mw0 = (const float*)d_in[35];
  const float* mb0 = (const float*)d_in[36];
  const float* mw1 = (const float*)d_in[37];
  const float* mb1 = (const float*)d_in[38];
  float* out = (float*)d_out;

  char* w = (char*)d_ws;
  size_t off = 0;
  auto alloc = [&](size_t b) -> void* {
    void* p = w + off;
    off = (off + b + 255) & ~(size_t)255;
    return p;
  };
  int* cnt_row  = (int*)alloc(sizeof(int) * NN);
  int* cnt_col  = (int*)alloc(sizeof(int) * NN);
  int* row_off  = (int*)alloc(sizeof(int) * (NN + 1));
  int* col_off  = (int*)alloc(sizeof(int) * (NN + 1));
  int* cur_row  = (int*)alloc(sizeof(int) * NN);
  int* cur_col  = (int*)alloc(sizeof(int) * NN);
  int* eid_row  = (int*)alloc(sizeof(int) * NE);
  int* slot_col = (int*)alloc(sizeof(int) * NE);
  float* xb0  = (float*)alloc(sizeof(float) * NN * 32);
  float* xb1  = (float*)alloc(sizeof(float) * NN * 32);
  float* xp   = (float*)alloc(sizeof(float) * NN * 32);
  float* root = (float*)alloc(sizeof(float) * NN * 32);
  float* Bb   = (float*)alloc(sizeof(float) * NN * 32);
  float* msg  = (float*)alloc(sizeof(float) * NE * 32);
  float* Vb   = (float*)alloc(sizeof(float) * 128 * 32 * 32);  // 512 KB max
  float* U = (float*)(w + off);
  size_t uavail = (ws_size > off) ? (ws_size - off) : 0;

  hipMemsetAsync(cnt_row, 0, sizeof(int) * NN, stream);
  hipMemsetAsync(cnt_col, 0, sizeof(int) * NN, stream);
  k_count<<<(NE + TPB - 1) / TPB, TPB, 0, stream>>>(ei, cnt_row, cnt_col);
  k_scan2<<<2, 64, 0, stream>>>(cnt_row, row_off, cur_row, cnt_col, col_off, cur_col);
  k_fill_row<<<(NE + TPB - 1) / TPB, TPB, 0, stream>>>(ei, cur_row, eid_row);
  k_fill_col<<<(NE + TPB - 1) / TPB, TPB, 0, stream>>>(ei, eid_row, cur_col, slot_col);

  float* bufs[2] = {xb0, xb1};
  const float* xin = x0;
  for (int l = 0; l < 4; l++) {
    float* xout = bufs[l & 1];
    if (l == 0) {
      run_layer<16, 32>(xin, xout, L[0], ei, ea, row_off, col_off, eid_row, slot_col,
                        xp, root, Bb, msg, Vb, U, uavail, stream);
    } else if (l == 1) {
      run_layer<32, 16>(xin, xout, L[1], ei, ea, row_off, col_off, eid_row, slot_col,
                        xp, root, Bb, msg, Vb, U, uavail, stream);
    } else if (l == 2) {
      run_layer<16, 16>(xin, xout, L[2], ei, ea, row_off, col_off, eid_row, slot_col,
                        xp, root, Bb, msg, Vb, U, uavail, stream);
    } else {
      run_layer<16, 16>(xin, xout, L[3], ei, ea, row_off, col_off, eid_row, slot_col,
                        xp, root, Bb, msg, Vb, U, uavail, stream);
    }
    xin = xout;
  }
  k_final<<<(NE + TPB - 1) / TPB, TPB, 0, stream>>>(ei, xin, mw0, mb0, mw1, mb1, out);
}